// Round 2
// baseline (3143.675 us; speedup 1.0000x reference)
//
#include <hip/hip_runtime.h>
#include <hip/hip_bf16.h>
#include <math.h>

// Dims (fixed by problem)
#define NL 6
#define DMODEL 1024
#define NHEAD 16
#define MTOT 8192      // B*N = 2*4096
#define NSEQ 4096
#define FFDIM 4096

typedef __attribute__((ext_vector_type(8))) short bf16x8;
typedef __attribute__((ext_vector_type(4))) short s16x4;
typedef __attribute__((ext_vector_type(4))) float f32x4;

__device__ __forceinline__ float b2f(short s) {
    unsigned int u = ((unsigned int)(unsigned short)s) << 16;
    return __uint_as_float(u);
}
__device__ __forceinline__ short f2b(float f) {
    __hip_bfloat16 h = __float2bfloat16(f);
    return *reinterpret_cast<short*>(&h);
}
__device__ __forceinline__ f32x4 mfma16(bf16x8 a, bf16x8 b, f32x4 c) {
    return __builtin_amdgcn_mfma_f32_16x16x32_bf16(a, b, c, 0, 0, 0);
}
__device__ __forceinline__ void gload16(const void* g, void* lds) {
    __builtin_amdgcn_global_load_lds((__attribute__((address_space(1))) void*)(g),
                                     (__attribute__((address_space(3))) void*)(lds), 16, 0, 0);
}

// ---------------- f32 -> bf16 weight convert (vectorized x4) ----------------
__global__ __launch_bounds__(256) void cvt_f2b_kernel(const float* __restrict__ in,
        short* __restrict__ out, int n4) {
    int i = blockIdx.x * 256 + threadIdx.x;
    if (i >= n4) return;
    float4 v = ((const float4*)in)[i];
    s16x4 o;
    o[0] = f2b(v.x); o[1] = f2b(v.y); o[2] = f2b(v.z); o[3] = f2b(v.w);
    ((s16x4*)out)[i] = o;
}

// ---------------- embedding: x = tok_emb[tok] + pos_emb[n]  (f32 in/out) ----
__global__ __launch_bounds__(256) void embed_kernel(const int* __restrict__ tok,
        const float* __restrict__ te, const float* __restrict__ pe, float* __restrict__ x) {
    int row = blockIdx.x, tid = threadIdx.x;
    int t = tok[row], n = row & (NSEQ - 1);
    float4 a = ((const float4*)(te + (size_t)t * DMODEL))[tid];
    float4 p = ((const float4*)(pe + (size_t)n * DMODEL))[tid];
    float4 o;
    o.x = a.x + p.x; o.y = a.y + p.y; o.z = a.z + p.z; o.w = a.w + p.w;
    ((float4*)(x + (size_t)row * DMODEL))[tid] = o;
}

// ---------------- Wcomb: [Wphi_q(1024); Wphi_k(1024); Wv(1024)] per layer ---
// Wphi[h*64+r, c] = sum_d rf[h,d,r] * Wq[h*64+d, c]   (f32 in, bf16 out)
__global__ __launch_bounds__(256) void prep_wcomb(const float* __restrict__ Wqkv,
        const float* __restrict__ rf, short* __restrict__ Wcomb) {
    int id = blockIdx.x;
    int l = id / 3072, row = id % 3072;
    int tid = threadIdx.x;
    size_t outbase = ((size_t)l * 3072 + row) * DMODEL;
    if (row >= 2048) {  // v rows: passthrough convert
        #pragma unroll
        for (int it = 0; it < 4; it++)
            Wcomb[outbase + it * 256 + tid] = f2b(Wqkv[outbase + it * 256 + tid]);
        return;
    }
    int base = (row < 1024) ? 0 : 1024;
    int hh = (row & 1023) >> 6, r = row & 63;
    __shared__ float rfl[64];
    if (tid < 64) rfl[tid] = rf[(((size_t)l * NHEAD + hh) * 64 + tid) * 64 + r];
    __syncthreads();
    #pragma unroll
    for (int it = 0; it < 4; it++) {
        int k = it * 256 + tid;
        float acc = 0.f;
        #pragma unroll 8
        for (int d = 0; d < 64; d++)
            acc += rfl[d] * Wqkv[((size_t)l * 3072 + base + hh * 64 + d) * DMODEL + k];
        Wcomb[outbase + k] = f2b(acc);
    }
}

// ---------------- LayerNorm (f32 in, bf16 out) ------------------------------
__global__ __launch_bounds__(256) void ln_kernel(const float* __restrict__ x,
        const float* __restrict__ g, const float* __restrict__ bta, short* __restrict__ h) {
    int row = blockIdx.x, tid = threadIdx.x, lane = tid & 63, w = tid >> 6;
    float4 v = ((const float4*)(x + (size_t)row * DMODEL))[tid];
    float s = v.x + v.y + v.z + v.w;
    float sq = v.x * v.x + v.y * v.y + v.z * v.z + v.w * v.w;
    #pragma unroll
    for (int off = 32; off > 0; off >>= 1) { s += __shfl_down(s, off); sq += __shfl_down(sq, off); }
    __shared__ float ss[4], sqq[4];
    if (lane == 0) { ss[w] = s; sqq[w] = sq; }
    __syncthreads();
    float st = ss[0] + ss[1] + ss[2] + ss[3];
    float sqt = sqq[0] + sqq[1] + sqq[2] + sqq[3];
    float mean = st * (1.f / 1024.f);
    float var = sqt * (1.f / 1024.f) - mean * mean;
    float rstd = rsqrtf(var + 1e-5f);
    int col = tid * 4;
    float4 gg = ((const float4*)g)[tid];
    float4 bb = ((const float4*)bta)[tid];
    s16x4 o;
    o[0] = f2b((v.x - mean) * rstd * gg.x + bb.x);
    o[1] = f2b((v.y - mean) * rstd * gg.y + bb.y);
    o[2] = f2b((v.z - mean) * rstd * gg.z + bb.z);
    o[3] = f2b((v.w - mean) * rstd * gg.w + bb.w);
    *(s16x4*)&h[(size_t)row * DMODEL + col] = o;
}

// ---------------- main GEMM: C = A[M,K] * B[N,K]^T, bf16 in, fused epilogues
#define EPI_QKV 0
#define EPI_BIASRES 1
#define EPI_GELU 2

template <int EPI>
__global__ __launch_bounds__(256) void gemm_bt(const short* __restrict__ A,
        const short* __restrict__ B, int K, int N,
        const float* __restrict__ bias, float* __restrict__ resx,
        short* __restrict__ out0, short* __restrict__ out1, short* __restrict__ out2) {
    __shared__ short As[128 * 32];
    __shared__ short Bs[128 * 32];
    const int tid = threadIdx.x;
    const int lane = tid & 63;
    const int w = tid >> 6;
    const int bn = blockIdx.x, bm = blockIdx.y;
    const int warow = (w >> 1) * 64;
    const int wacol = (w & 1) * 64;
    const int q = lane >> 4;

    f32x4 acc[4][4];
    #pragma unroll
    for (int i = 0; i < 4; i++)
        #pragma unroll
        for (int j = 0; j < 4; j++)
            #pragma unroll
            for (int c = 0; c < 4; c++) acc[i][j][c] = 0.f;

    // staging slots: s = i*256 + tid ; row = s>>2 ; swizzled chunk j = (s&3)^((row>>1)&3)
    const int s0 = tid, s1 = 256 + tid;
    const int rowA0 = s0 >> 2, rowA1 = s1 >> 2;
    const int j0 = (s0 & 3) ^ ((rowA0 >> 1) & 3);
    const int j1 = (s1 & 3) ^ ((rowA1 >> 1) & 3);
    const size_t aBase0 = (size_t)(bm * 128 + rowA0) * K + j0 * 8;
    const size_t aBase1 = (size_t)(bm * 128 + rowA1) * K + j1 * 8;
    const size_t bBase0 = (size_t)(bn * 128 + rowA0) * K + j0 * 8;
    const size_t bBase1 = (size_t)(bn * 128 + rowA1) * K + j1 * 8;
    short* ldsA0 = &As[(s0 & ~63) * 8];
    short* ldsA1 = &As[(s1 & ~63) * 8];
    short* ldsB0 = &Bs[(s0 & ~63) * 8];
    short* ldsB1 = &Bs[(s1 & ~63) * 8];

    for (int k0 = 0; k0 < K; k0 += 32) {
        gload16(A + aBase0 + k0, ldsA0);
        gload16(A + aBase1 + k0, ldsA1);
        gload16(B + bBase0 + k0, ldsB0);
        gload16(B + bBase1 + k0, ldsB1);
        __syncthreads();
        bf16x8 af[4], bfr[4];
        #pragma unroll
        for (int mt = 0; mt < 4; mt++) {
            int m = warow + mt * 16 + (lane & 15);
            int jj = q ^ ((m >> 1) & 3);
            af[mt] = *(const bf16x8*)&As[m * 32 + jj * 8];
        }
        #pragma unroll
        for (int nt = 0; nt < 4; nt++) {
            int n = wacol + nt * 16 + (lane & 15);
            int jj = q ^ ((n >> 1) & 3);
            bfr[nt] = *(const bf16x8*)&Bs[n * 32 + jj * 8];
        }
        #pragma unroll
        for (int mt = 0; mt < 4; mt++)
            #pragma unroll
            for (int nt = 0; nt < 4; nt++)
                acc[mt][nt] = mfma16(af[mt], bfr[nt], acc[mt][nt]);
        __syncthreads();
    }

    // epilogue: C[row][col], row = bm*128+warow+mt*16+q*4+i, col = bn*128+wacol+nt*16+(lane&15)
    #pragma unroll
    for (int mt = 0; mt < 4; mt++) {
        int row0 = bm * 128 + warow + mt * 16 + (q << 2);
        #pragma unroll
        for (int nt = 0; nt < 4; nt++) {
            int col = bn * 128 + wacol + nt * 16 + (lane & 15);
            f32x4 v = acc[mt][nt];
            if (EPI == EPI_QKV) {
                if (col < 1024) {          // phi_q (relu), normal layout [m, h*64+r]
                    #pragma unroll
                    for (int i = 0; i < 4; i++)
                        out0[(size_t)(row0 + i) * DMODEL + col] = f2b(fmaxf(v[i], 0.f));
                } else if (col < 2048) {   // phi_k (relu), transposed [bh, r, n]
                    int c = col - 1024, hh = c >> 6, r = c & 63;
                    int b = row0 >> 12, n0 = row0 & (NSEQ - 1);
                    s16x4 pk;
                    #pragma unroll
                    for (int i = 0; i < 4; i++) pk[i] = f2b(fmaxf(v[i], 0.f));
                    *(s16x4*)&out1[((size_t)((b * NHEAD + hh) * 64 + r)) * NSEQ + n0] = pk;
                } else {                   // v, transposed [bh, d, n]
                    int c = col - 2048, hh = c >> 6, dd = c & 63;
                    int b = row0 >> 12, n0 = row0 & (NSEQ - 1);
                    s16x4 pk;
                    #pragma unroll
                    for (int i = 0; i < 4; i++) pk[i] = f2b(v[i]);
                    *(s16x4*)&out2[((size_t)((b * NHEAD + hh) * 64 + dd)) * NSEQ + n0] = pk;
                }
            } else if (EPI == EPI_BIASRES) {
                float bb = bias[col];
                #pragma unroll
                for (int i = 0; i < 4; i++) {
                    size_t idx = (size_t)(row0 + i) * N + col;
                    resx[idx] += v[i] + bb;
                }
            } else {  // EPI_GELU
                float bb = bias[col];
                #pragma unroll
                for (int i = 0; i < 4; i++) {
                    float t = v[i] + bb;
                    float gg = 0.5f * t * (1.f + erff(t * 0.70710678118654752f));
                    out0[(size_t)(row0 + i) * N + col] = f2b(gg);
                }
            }
        }
    }
}

// ---------------- kvT[d,r] = sum_n v[n,d] phi_k[n,r]  (split-K, f32 atomics)
__global__ __launch_bounds__(256) void zero_kvs(float* kvs) {
    int i = blockIdx.x * 256 + threadIdx.x;
    if (i < 32 * 65 * 64) kvs[i] = 0.f;
}

__global__ __launch_bounds__(256) void kv_kernel(const short* __restrict__ phiKT,
        const short* __restrict__ vT, float* __restrict__ kvs) {
    int bh = blockIdx.x;  // 0..31
    int kc = blockIdx.y;  // 0..7 (n-chunks of 512)
    int tid = threadIdx.x, lane = tid & 63, w = tid >> 6, q = lane >> 4;
    f32x4 acc[4];
    #pragma unroll
    for (int nt = 0; nt < 4; nt++)
        #pragma unroll
        for (int c = 0; c < 4; c++) acc[nt][c] = 0.f;
    const short* Abase = vT + ((size_t)(bh * 64 + w * 16 + (lane & 15))) * NSEQ;
    for (int ks = 0; ks < 16; ks++) {
        int k0 = kc * 512 + ks * 32 + q * 8;
        bf16x8 a = *(const bf16x8*)&Abase[k0];
        #pragma unroll
        for (int nt = 0; nt < 4; nt++) {
            bf16x8 b = *(const bf16x8*)&phiKT[((size_t)(bh * 64 + nt * 16 + (lane & 15))) * NSEQ + k0];
            acc[nt] = mfma16(a, b, acc[nt]);
        }
    }
    #pragma unroll
    for (int nt = 0; nt < 4; nt++)
        #pragma unroll
        for (int i = 0; i < 4; i++)
            atomicAdd(&kvs[((size_t)bh * 65 + (w * 16 + q * 4 + i)) * 64 + nt * 16 + (lane & 15)],
                      acc[nt][i]);
    // ksum partials: row 64
    int r = tid & 63, qq = tid >> 6;
    const short* p = phiKT + ((size_t)(bh * 64 + r)) * NSEQ + kc * 512 + qq * 128;
    float s = 0.f;
    #pragma unroll 8
    for (int u = 0; u < 128; u++) s += b2f(p[u]);
    __shared__ float red[256];
    red[tid] = s;
    __syncthreads();
    if (tid < 64) {
        float t = red[tid] + red[tid + 64] + red[tid + 128] + red[tid + 192];
        atomicAdd(&kvs[((size_t)bh * 65 + 64) * 64 + tid], t);
    }
}

__global__ __launch_bounds__(256) void cvt_kvs(const float* __restrict__ kvs,
        short* __restrict__ kvsb) {
    int bh = blockIdx.x, tid = threadIdx.x;
    for (int idx = tid; idx < 80 * 64; idx += 256) {
        int row = idx >> 6, col = idx & 63;
        float v = (row < 65) ? kvs[((size_t)bh * 65 + row) * 64 + col] : 0.f;
        kvsb[((size_t)bh * 80 + row) * 64 + col] = f2b(v);
    }
}

// ---------------- out[n, h*64+d] = (phi_q . kv) / (phi_q . ksum + 1e-6) -----
__global__ __launch_bounds__(256) void attn_kernel(const short* __restrict__ phiQ,
        const short* __restrict__ kvsb, short* __restrict__ attnO) {
    int mt = blockIdx.x;  // 0..63 (64-row tiles over seq)
    int bh = blockIdx.y;  // 0..31
    int b = bh >> 4, h = bh & 15;
    int tid = threadIdx.x, lane = tid & 63, w = tid >> 6, q = lane >> 4;
    int mrow = mt * 64 + w * 16 + (lane & 15);
    const short* Abase = phiQ + ((size_t)(b * NSEQ + mrow)) * DMODEL + h * 64;
    f32x4 acc[5];
    #pragma unroll
    for (int nt = 0; nt < 5; nt++)
        #pragma unroll
        for (int c = 0; c < 4; c++) acc[nt][c] = 0.f;
    #pragma unroll
    for (int k0 = 0; k0 < 64; k0 += 32) {
        bf16x8 a = *(const bf16x8*)&Abase[k0 + q * 8];
        #pragma unroll
        for (int nt = 0; nt < 5; nt++) {
            bf16x8 bb = *(const bf16x8*)&kvsb[((size_t)bh * 80 + nt * 16 + (lane & 15)) * 64 + k0 + q * 8];
            acc[nt] = mfma16(a, bb, acc[nt]);
        }
    }
    int n0 = mt * 64 + w * 16 + q * 4;
    #pragma unroll
    for (int i = 0; i < 4; i++) {
        float nz = __shfl(acc[4][i], (lane & 48)) + 1e-6f;  // col 64 = normalizer
        #pragma unroll
        for (int nt = 0; nt < 4; nt++) {
            float val = acc[nt][i] / nz;
            attnO[((size_t)(b * NSEQ + n0 + i)) * DMODEL + h * 64 + nt * 16 + (lane & 15)] = f2b(val);
        }
    }
}

// ---------------- final copy (f32 out) --------------------------------------
__global__ __launch_bounds__(256) void cvt_out(const float* __restrict__ x,
        float* __restrict__ out) {
    size_t i = (size_t)blockIdx.x * 256 + threadIdx.x;
    ((float4*)out)[i] = ((const float4*)x)[i];
}

extern "C" void kernel_launch(void* const* d_in, const int* in_sizes, int n_in,
                              void* d_out, int out_size, void* d_ws, size_t ws_size,
                              hipStream_t stream) {
    const int* tokens = (const int*)d_in[0];
    const float* tok_emb = (const float*)d_in[1];
    const float* pos_emb = (const float*)d_in[2];
    const float* Wqkv = (const float*)d_in[3];
    const float* Wout = (const float*)d_in[4];
    const float* bout = (const float*)d_in[5];
    const float* ln1g = (const float*)d_in[6];
    const float* ln1b = (const float*)d_in[7];
    const float* ln2g = (const float*)d_in[8];
    const float* ln2b = (const float*)d_in[9];
    const float* W1 = (const float*)d_in[10];
    const float* b1 = (const float*)d_in[11];
    const float* W2 = (const float*)d_in[12];
    const float* b2 = (const float*)d_in[13];
    const float* rf = (const float*)d_in[14];

    char* ws = (char*)d_ws;
    float* x      = (float*)ws;                           // 33,554,432 B
    short* Wcomb  = (short*)(ws + 33554432);              // 37,748,736 B
    short* WoutB  = (short*)(ws + 71303168);              // 12,582,912 B
    short* W1B    = (short*)(ws + 83886080);              // 50,331,648 B
    short* W2B    = (short*)(ws + 134217728);             // 50,331,648 B
    short* h      = (short*)(ws + 184549376);             // 16,777,216 B
    short* phiQ   = (short*)(ws + 201326592);             // 16,777,216 B
    short* phiKT  = (short*)(ws + 218103808);             // 16,777,216 B
    short* vT     = (short*)(ws + 234881024);             // 16,777,216 B
    short* attnO  = (short*)(ws + 251658240);             // 16,777,216 B
    short* ff     = phiQ;                                 // overlay (67,108,864 B exact)
    float* kvs    = (float*)(ws + 268435456);             // 532,480 B
    short* kvsb   = (short*)(ws + 268967936);             // 327,680 B
    // total: 269,295,616 B

    embed_kernel<<<MTOT, 256, 0, stream>>>(tokens, tok_emb, pos_emb, x);
    prep_wcomb<<<NL * 3072, 256, 0, stream>>>(Wqkv, rf, Wcomb);
    cvt_f2b_kernel<<<(NL * 1024 * 1024 / 4 + 255) / 256, 256, 0, stream>>>(Wout, WoutB, NL * 1024 * 1024 / 4);
    cvt_f2b_kernel<<<(NL * 4096 * 1024 / 4 + 255) / 256, 256, 0, stream>>>(W1, W1B, NL * 4096 * 1024 / 4);
    cvt_f2b_kernel<<<(NL * 1024 * 4096 / 4 + 255) / 256, 256, 0, stream>>>(W2, W2B, NL * 1024 * 4096 / 4);

    for (int l = 0; l < NL; l++) {
        ln_kernel<<<MTOT, 256, 0, stream>>>(x, ln1g + l * 1024, ln1b + l * 1024, h);
        gemm_bt<EPI_QKV><<<dim3(24, 64), 256, 0, stream>>>(
            h, Wcomb + (size_t)l * 3072 * 1024, 1024, 3072,
            nullptr, nullptr, phiQ, phiKT, vT);
        zero_kvs<<<520, 256, 0, stream>>>(kvs);
        kv_kernel<<<dim3(32, 8), 256, 0, stream>>>(phiKT, vT, kvs);
        cvt_kvs<<<32, 256, 0, stream>>>(kvs, kvsb);
        attn_kernel<<<dim3(64, 32), 256, 0, stream>>>(phiQ, kvsb, attnO);
        gemm_bt<EPI_BIASRES><<<dim3(8, 64), 256, 0, stream>>>(
            attnO, WoutB + (size_t)l * 1024 * 1024, 1024, 1024,
            bout + l * 1024, x, nullptr, nullptr, nullptr);
        ln_kernel<<<MTOT, 256, 0, stream>>>(x, ln2g + l * 1024, ln2b + l * 1024, h);
        gemm_bt<EPI_GELU><<<dim3(32, 64), 256, 0, stream>>>(
            h, W1B + (size_t)l * 4096 * 1024, 1024, 4096,
            b1 + l * 4096, nullptr, ff, nullptr, nullptr);
        gemm_bt<EPI_BIASRES><<<dim3(8, 64), 256, 0, stream>>>(
            ff, W2B + (size_t)l * 1024 * 4096, 4096, 1024,
            b2 + l * 1024, x, nullptr, nullptr, nullptr);
    }
    cvt_out<<<MTOT * DMODEL / 1024, 256, 0, stream>>>(x, (float*)d_out);
}

// Round 3
// 2613.153 us; speedup vs baseline: 1.2030x; 1.2030x over previous
//
#include <hip/hip_runtime.h>
#include <hip/hip_bf16.h>
#include <math.h>

// Dims (fixed by problem)
#define NL 6
#define DMODEL 1024
#define NHEAD 16
#define MTOT 8192      // B*N = 2*4096
#define NSEQ 4096
#define FFDIM 4096

typedef __attribute__((ext_vector_type(8))) short bf16x8;
typedef __attribute__((ext_vector_type(4))) short s16x4;
typedef __attribute__((ext_vector_type(4))) float f32x4;

__device__ __forceinline__ float b2f(short s) {
    unsigned int u = ((unsigned int)(unsigned short)s) << 16;
    return __uint_as_float(u);
}
__device__ __forceinline__ short f2b(float f) {
    __hip_bfloat16 h = __float2bfloat16(f);
    return *reinterpret_cast<short*>(&h);
}
__device__ __forceinline__ f32x4 mfma16(bf16x8 a, bf16x8 b, f32x4 c) {
    return __builtin_amdgcn_mfma_f32_16x16x32_bf16(a, b, c, 0, 0, 0);
}
__device__ __forceinline__ void gload16(const void* g, void* lds) {
    __builtin_amdgcn_global_load_lds((__attribute__((address_space(1))) void*)(g),
                                     (__attribute__((address_space(3))) void*)(lds), 16, 0, 0);
}

// ---------------- f32 -> bf16 weight convert (vectorized x4) ----------------
__global__ __launch_bounds__(256) void cvt_f2b_kernel(const float* __restrict__ in,
        short* __restrict__ out, int n4) {
    int i = blockIdx.x * 256 + threadIdx.x;
    if (i >= n4) return;
    float4 v = ((const float4*)in)[i];
    s16x4 o;
    o[0] = f2b(v.x); o[1] = f2b(v.y); o[2] = f2b(v.z); o[3] = f2b(v.w);
    ((s16x4*)out)[i] = o;
}

// ---------------- embedding: x = tok_emb[tok] + pos_emb[n]  (f32 in/out) ----
__global__ __launch_bounds__(256) void embed_kernel(const int* __restrict__ tok,
        const float* __restrict__ te, const float* __restrict__ pe, float* __restrict__ x) {
    int row = blockIdx.x, tid = threadIdx.x;
    int t = tok[row], n = row & (NSEQ - 1);
    float4 a = ((const float4*)(te + (size_t)t * DMODEL))[tid];
    float4 p = ((const float4*)(pe + (size_t)n * DMODEL))[tid];
    float4 o;
    o.x = a.x + p.x; o.y = a.y + p.y; o.z = a.z + p.z; o.w = a.w + p.w;
    ((float4*)(x + (size_t)row * DMODEL))[tid] = o;
}

// ---------------- prep_phi: Wphi[h*64+r, k] = sum_d rf[l,h,d,r]*Wqk[h*64+d, k]
// grid 768 = (l 6) x (h 16) x (qk 2) x (kc 4); each Wq element read ONCE.
__global__ __launch_bounds__(256) void prep_phi(const float* __restrict__ Wqkv,
        const float* __restrict__ rf, short* __restrict__ Wcomb) {
    int b = blockIdx.x;
    int kc = b & 3, qk = (b >> 2) & 1, h = (b >> 3) & 15, l = b >> 7;
    int tid = threadIdx.x;
    // stage rf[l,h] (64 d x 64 r, f32) into LDS, linear copy
    __shared__ float rfl[64 * 64];
    const float* rfg = rf + ((size_t)(l * NHEAD + h)) * 4096;
    #pragma unroll
    for (int u = 0; u < 4; u++) {
        int i4 = u * 256 + tid;
        ((float4*)rfl)[i4] = ((const float4*)rfg)[i4];
    }
    __syncthreads();
    int k = kc * 256 + tid;
    const float* wq = Wqkv + ((size_t)(l * 3072 + qk * 1024 + h * 64)) * DMODEL + k;
    float acc[64];
    #pragma unroll
    for (int r = 0; r < 64; r++) acc[r] = 0.f;
    #pragma unroll 4
    for (int d = 0; d < 64; d++) {
        float wd = wq[(size_t)d * DMODEL];
        const float4* rrow = (const float4*)&rfl[d * 64];
        #pragma unroll
        for (int r4 = 0; r4 < 16; r4++) {
            float4 f = rrow[r4];   // broadcast LDS read, conflict-free
            acc[r4 * 4 + 0] += f.x * wd;
            acc[r4 * 4 + 1] += f.y * wd;
            acc[r4 * 4 + 2] += f.z * wd;
            acc[r4 * 4 + 3] += f.w * wd;
        }
    }
    size_t outbase = ((size_t)(l * 3072 + qk * 1024 + h * 64)) * DMODEL + k;
    #pragma unroll
    for (int r = 0; r < 64; r++)
        Wcomb[outbase + (size_t)r * DMODEL] = f2b(acc[r]);
}

// ---------------- prep_v: passthrough convert of V rows ---------------------
__global__ __launch_bounds__(256) void prep_v(const float* __restrict__ Wqkv,
        short* __restrict__ Wcomb) {
    int b = blockIdx.x;
    int l = b >> 10, row = b & 1023;
    int tid = threadIdx.x;
    size_t base = ((size_t)(l * 3072 + 2048 + row)) * DMODEL;
    float4 v = ((const float4*)(Wqkv + base))[tid];
    s16x4 o;
    o[0] = f2b(v.x); o[1] = f2b(v.y); o[2] = f2b(v.z); o[3] = f2b(v.w);
    ((s16x4*)(Wcomb + base))[tid] = o;
}

// ---------------- LayerNorm (f32 in, bf16 out) ------------------------------
__global__ __launch_bounds__(256) void ln_kernel(const float* __restrict__ x,
        const float* __restrict__ g, const float* __restrict__ bta, short* __restrict__ h) {
    int row = blockIdx.x, tid = threadIdx.x, lane = tid & 63, w = tid >> 6;
    float4 v = ((const float4*)(x + (size_t)row * DMODEL))[tid];
    float s = v.x + v.y + v.z + v.w;
    float sq = v.x * v.x + v.y * v.y + v.z * v.z + v.w * v.w;
    #pragma unroll
    for (int off = 32; off > 0; off >>= 1) { s += __shfl_down(s, off); sq += __shfl_down(sq, off); }
    __shared__ float ss[4], sqq[4];
    if (lane == 0) { ss[w] = s; sqq[w] = sq; }
    __syncthreads();
    float st = ss[0] + ss[1] + ss[2] + ss[3];
    float sqt = sqq[0] + sqq[1] + sqq[2] + sqq[3];
    float mean = st * (1.f / 1024.f);
    float var = sqt * (1.f / 1024.f) - mean * mean;
    float rstd = rsqrtf(var + 1e-5f);
    int col = tid * 4;
    float4 gg = ((const float4*)g)[tid];
    float4 bb = ((const float4*)bta)[tid];
    s16x4 o;
    o[0] = f2b((v.x - mean) * rstd * gg.x + bb.x);
    o[1] = f2b((v.y - mean) * rstd * gg.y + bb.y);
    o[2] = f2b((v.z - mean) * rstd * gg.z + bb.z);
    o[3] = f2b((v.w - mean) * rstd * gg.w + bb.w);
    *(s16x4*)&h[(size_t)row * DMODEL + col] = o;
}

// ---------------- main GEMM: C = A[M,K] * B[N,K]^T, BK=64, fused epilogues --
#define EPI_QKV 0
#define EPI_BIASRES 1
#define EPI_GELU 2

template <int EPI>
__global__ __launch_bounds__(256, 3) void gemm_bt(const short* __restrict__ A,
        const short* __restrict__ B, int K, int N,
        const float* __restrict__ bias, float* __restrict__ resx,
        short* __restrict__ out0, short* __restrict__ out1, short* __restrict__ out2) {
    __shared__ short As[128 * 64];   // 16 KB
    __shared__ short Bs[128 * 64];   // 16 KB
    const int tid = threadIdx.x;
    const int lane = tid & 63;
    const int w = tid >> 6;
    const int bn = blockIdx.x, bm = blockIdx.y;
    const int warow = (w >> 1) * 64;
    const int wacol = (w & 1) * 64;
    const int q = lane >> 4;

    f32x4 acc[4][4];
    #pragma unroll
    for (int i = 0; i < 4; i++)
        #pragma unroll
        for (int j = 0; j < 4; j++)
            #pragma unroll
            for (int c = 0; c < 4; c++) acc[i][j][c] = 0.f;

    // staging: 1024 slots of 16B per array; slot s -> row=s>>3, phys chunk cp=s&7,
    // holds global chunk j = cp ^ ((row>>1)&7). LDS dst linear in s (wave-uniform+lane*16).
    unsigned aOff[4], bOff[4];
    short* ldsA[4];
    short* ldsB[4];
    #pragma unroll
    for (int i = 0; i < 4; i++) {
        int s = i * 256 + tid;
        int row = s >> 3, cp = s & 7;
        int j = cp ^ ((row >> 1) & 7);
        aOff[i] = (unsigned)((bm * 128 + row) * K + j * 8);
        bOff[i] = (unsigned)((bn * 128 + row) * K + j * 8);
        ldsA[i] = &As[s * 8];
        ldsB[i] = &Bs[s * 8];
    }

    for (int k0 = 0; k0 < K; k0 += 64) {
        #pragma unroll
        for (int i = 0; i < 4; i++) gload16(A + aOff[i] + k0, ldsA[i]);
        #pragma unroll
        for (int i = 0; i < 4; i++) gload16(B + bOff[i] + k0, ldsB[i]);
        __syncthreads();
        #pragma unroll
        for (int ksub = 0; ksub < 2; ksub++) {
            bf16x8 af[4], bfr[4];
            #pragma unroll
            for (int mt = 0; mt < 4; mt++) {
                int m = warow + mt * 16 + (lane & 15);
                int c = (ksub * 4 + q) ^ ((m >> 1) & 7);
                af[mt] = *(const bf16x8*)&As[m * 64 + c * 8];
            }
            #pragma unroll
            for (int nt = 0; nt < 4; nt++) {
                int n = wacol + nt * 16 + (lane & 15);
                int c = (ksub * 4 + q) ^ ((n >> 1) & 7);
                bfr[nt] = *(const bf16x8*)&Bs[n * 64 + c * 8];
            }
            #pragma unroll
            for (int mt = 0; mt < 4; mt++)
                #pragma unroll
                for (int nt = 0; nt < 4; nt++)
                    acc[mt][nt] = mfma16(af[mt], bfr[nt], acc[mt][nt]);
        }
        __syncthreads();
    }

    // epilogue: row = bm*128+warow+mt*16+q*4+i, col = bn*128+wacol+nt*16+(lane&15)
    #pragma unroll
    for (int mt = 0; mt < 4; mt++) {
        int row0 = bm * 128 + warow + mt * 16 + (q << 2);
        #pragma unroll
        for (int nt = 0; nt < 4; nt++) {
            int col = bn * 128 + wacol + nt * 16 + (lane & 15);
            f32x4 v = acc[mt][nt];
            if (EPI == EPI_QKV) {
                if (col < 1024) {          // phi_q (relu), [m, h*64+r]
                    #pragma unroll
                    for (int i = 0; i < 4; i++)
                        out0[(size_t)(row0 + i) * DMODEL + col] = f2b(fmaxf(v[i], 0.f));
                } else if (col < 2048) {   // phi_k (relu), transposed [bh, r, n]
                    int c = col - 1024, hh = c >> 6, r = c & 63;
                    int b = row0 >> 12, n0 = row0 & (NSEQ - 1);
                    s16x4 pk;
                    #pragma unroll
                    for (int i = 0; i < 4; i++) pk[i] = f2b(fmaxf(v[i], 0.f));
                    *(s16x4*)&out1[((size_t)((b * NHEAD + hh) * 64 + r)) * NSEQ + n0] = pk;
                } else {                   // v, transposed [bh, d, n]
                    int c = col - 2048, hh = c >> 6, dd = c & 63;
                    int b = row0 >> 12, n0 = row0 & (NSEQ - 1);
                    s16x4 pk;
                    #pragma unroll
                    for (int i = 0; i < 4; i++) pk[i] = f2b(v[i]);
                    *(s16x4*)&out2[((size_t)((b * NHEAD + hh) * 64 + dd)) * NSEQ + n0] = pk;
                }
            } else if (EPI == EPI_BIASRES) {
                float bb = bias[col];
                #pragma unroll
                for (int i = 0; i < 4; i++) {
                    size_t idx = (size_t)(row0 + i) * N + col;
                    resx[idx] += v[i] + bb;
                }
            } else {  // EPI_GELU
                float bb = bias[col];
                #pragma unroll
                for (int i = 0; i < 4; i++) {
                    float t = v[i] + bb;
                    float gg = 0.5f * t * (1.f + erff(t * 0.70710678118654752f));
                    out0[(size_t)(row0 + i) * N + col] = f2b(gg);
                }
            }
        }
    }
}

// ---------------- kvT[d,r] = sum_n v[n,d] phi_k[n,r]  (split-K, f32 atomics)
__global__ __launch_bounds__(256) void zero_kvs(float* kvs) {
    int i = blockIdx.x * 256 + threadIdx.x;
    if (i < 32 * 65 * 64) kvs[i] = 0.f;
}

__global__ __launch_bounds__(256) void kv_kernel(const short* __restrict__ phiKT,
        const short* __restrict__ vT, float* __restrict__ kvs) {
    int bh = blockIdx.x;  // 0..31
    int kc = blockIdx.y;  // 0..7 (n-chunks of 512)
    int tid = threadIdx.x, lane = tid & 63, w = tid >> 6, q = lane >> 4;
    f32x4 acc[4];
    #pragma unroll
    for (int nt = 0; nt < 4; nt++)
        #pragma unroll
        for (int c = 0; c < 4; c++) acc[nt][c] = 0.f;
    const short* Abase = vT + ((size_t)(bh * 64 + w * 16 + (lane & 15))) * NSEQ;
    for (int ks = 0; ks < 16; ks++) {
        int k0 = kc * 512 + ks * 32 + q * 8;
        bf16x8 a = *(const bf16x8*)&Abase[k0];
        #pragma unroll
        for (int nt = 0; nt < 4; nt++) {
            bf16x8 b = *(const bf16x8*)&phiKT[((size_t)(bh * 64 + nt * 16 + (lane & 15))) * NSEQ + k0];
            acc[nt] = mfma16(a, b, acc[nt]);
        }
    }
    #pragma unroll
    for (int nt = 0; nt < 4; nt++)
        #pragma unroll
        for (int i = 0; i < 4; i++)
            atomicAdd(&kvs[((size_t)bh * 65 + (w * 16 + q * 4 + i)) * 64 + nt * 16 + (lane & 15)],
                      acc[nt][i]);
    // ksum partials: row 64
    int r = tid & 63, qq = tid >> 6;
    const short* p = phiKT + ((size_t)(bh * 64 + r)) * NSEQ + kc * 512 + qq * 128;
    float s = 0.f;
    #pragma unroll 8
    for (int u = 0; u < 128; u++) s += b2f(p[u]);
    __shared__ float red[256];
    red[tid] = s;
    __syncthreads();
    if (tid < 64) {
        float t = red[tid] + red[tid + 64] + red[tid + 128] + red[tid + 192];
        atomicAdd(&kvs[((size_t)bh * 65 + 64) * 64 + tid], t);
    }
}

__global__ __launch_bounds__(256) void cvt_kvs(const float* __restrict__ kvs,
        short* __restrict__ kvsb) {
    int bh = blockIdx.x, tid = threadIdx.x;
    for (int idx = tid; idx < 80 * 64; idx += 256) {
        int row = idx >> 6, col = idx & 63;
        float v = (row < 65) ? kvs[((size_t)bh * 65 + row) * 64 + col] : 0.f;
        kvsb[((size_t)bh * 80 + row) * 64 + col] = f2b(v);
    }
}

// ---------------- out[n, h*64+d] = (phi_q . kv) / (phi_q . ksum + 1e-6) -----
__global__ __launch_bounds__(256) void attn_kernel(const short* __restrict__ phiQ,
        const short* __restrict__ kvsb, short* __restrict__ attnO) {
    int mt = blockIdx.x;  // 0..63
    int bh = blockIdx.y;  // 0..31
    int b = bh >> 4, h = bh & 15;
    int tid = threadIdx.x, lane = tid & 63, w = tid >> 6, q = lane >> 4;
    int mrow = mt * 64 + w * 16 + (lane & 15);
    const short* Abase = phiQ + ((size_t)(b * NSEQ + mrow)) * DMODEL + h * 64;
    f32x4 acc[5];
    #pragma unroll
    for (int nt = 0; nt < 5; nt++)
        #pragma unroll
        for (int c = 0; c < 4; c++) acc[nt][c] = 0.f;
    #pragma unroll
    for (int k0 = 0; k0 < 64; k0 += 32) {
        bf16x8 a = *(const bf16x8*)&Abase[k0 + q * 8];
        #pragma unroll
        for (int nt = 0; nt < 5; nt++) {
            bf16x8 bb = *(const bf16x8*)&kvsb[((size_t)bh * 80 + nt * 16 + (lane & 15)) * 64 + k0 + q * 8];
            acc[nt] = mfma16(a, bb, acc[nt]);
        }
    }
    int n0 = mt * 64 + w * 16 + q * 4;
    #pragma unroll
    for (int i = 0; i < 4; i++) {
        float nz = __shfl(acc[4][i], (lane & 48)) + 1e-6f;
        #pragma unroll
        for (int nt = 0; nt < 4; nt++) {
            float val = acc[nt][i] / nz;
            attnO[((size_t)(b * NSEQ + n0 + i)) * DMODEL + h * 64 + nt * 16 + (lane & 15)] = f2b(val);
        }
    }
}

// ---------------- final copy (f32 out) --------------------------------------
__global__ __launch_bounds__(256) void cvt_out(const float* __restrict__ x,
        float* __restrict__ out) {
    size_t i = (size_t)blockIdx.x * 256 + threadIdx.x;
    ((float4*)out)[i] = ((const float4*)x)[i];
}

extern "C" void kernel_launch(void* const* d_in, const int* in_sizes, int n_in,
                              void* d_out, int out_size, void* d_ws, size_t ws_size,
                              hipStream_t stream) {
    const int* tokens = (const int*)d_in[0];
    const float* tok_emb = (const float*)d_in[1];
    const float* pos_emb = (const float*)d_in[2];
    const float* Wqkv = (const float*)d_in[3];
    const float* Wout = (const float*)d_in[4];
    const float* bout = (const float*)d_in[5];
    const float* ln1g = (const float*)d_in[6];
    const float* ln1b = (const float*)d_in[7];
    const float* ln2g = (const float*)d_in[8];
    const float* ln2b = (const float*)d_in[9];
    const float* W1 = (const float*)d_in[10];
    const float* b1 = (const float*)d_in[11];
    const float* W2 = (const float*)d_in[12];
    const float* b2 = (const float*)d_in[13];
    const float* rf = (const float*)d_in[14];

    char* ws = (char*)d_ws;
    float* x      = (float*)ws;                           // 33,554,432 B
    short* Wcomb  = (short*)(ws + 33554432);              // 37,748,736 B
    short* WoutB  = (short*)(ws + 71303168);              // 12,582,912 B
    short* W1B    = (short*)(ws + 83886080);              // 50,331,648 B
    short* W2B    = (short*)(ws + 134217728);             // 50,331,648 B
    short* h      = (short*)(ws + 184549376);             // 16,777,216 B
    short* phiQ   = (short*)(ws + 201326592);             // 16,777,216 B
    short* phiKT  = (short*)(ws + 218103808);             // 16,777,216 B
    short* vT     = (short*)(ws + 234881024);             // 16,777,216 B
    short* attnO  = (short*)(ws + 251658240);             // 16,777,216 B
    short* ff     = phiQ;                                 // overlay
    float* kvs    = (float*)(ws + 268435456);             // 532,480 B
    short* kvsb   = (short*)(ws + 268967936);             // 327,680 B

    embed_kernel<<<MTOT, 256, 0, stream>>>(tokens, tok_emb, pos_emb, x);
    prep_phi<<<768, 256, 0, stream>>>(Wqkv, rf, Wcomb);
    prep_v<<<NL * 1024, 256, 0, stream>>>(Wqkv, Wcomb);
    cvt_f2b_kernel<<<(NL * 1024 * 1024 / 4 + 255) / 256, 256, 0, stream>>>(Wout, WoutB, NL * 1024 * 1024 / 4);
    cvt_f2b_kernel<<<(NL * 4096 * 1024 / 4 + 255) / 256, 256, 0, stream>>>(W1, W1B, NL * 4096 * 1024 / 4);
    cvt_f2b_kernel<<<(NL * 1024 * 4096 / 4 + 255) / 256, 256, 0, stream>>>(W2, W2B, NL * 1024 * 4096 / 4);

    for (int l = 0; l < NL; l++) {
        ln_kernel<<<MTOT, 256, 0, stream>>>(x, ln1g + l * 1024, ln1b + l * 1024, h);
        gemm_bt<EPI_QKV><<<dim3(24, 64), 256, 0, stream>>>(
            h, Wcomb + (size_t)l * 3072 * 1024, 1024, 3072,
            nullptr, nullptr, phiQ, phiKT, vT);
        zero_kvs<<<520, 256, 0, stream>>>(kvs);
        kv_kernel<<<dim3(32, 8), 256, 0, stream>>>(phiKT, vT, kvs);
        cvt_kvs<<<32, 256, 0, stream>>>(kvs, kvsb);
        attn_kernel<<<dim3(64, 32), 256, 0, stream>>>(phiQ, kvsb, attnO);
        gemm_bt<EPI_BIASRES><<<dim3(8, 64), 256, 0, stream>>>(
            attnO, WoutB + (size_t)l * 1024 * 1024, 1024, 1024,
            bout + l * 1024, x, nullptr, nullptr, nullptr);
        ln_kernel<<<MTOT, 256, 0, stream>>>(x, ln2g + l * 1024, ln2b + l * 1024, h);
        gemm_bt<EPI_GELU><<<dim3(32, 64), 256, 0, stream>>>(
            h, W1B + (size_t)l * 4096 * 1024, 1024, 4096,
            b1 + l * 4096, nullptr, ff, nullptr, nullptr);
        gemm_bt<EPI_BIASRES><<<dim3(8, 64), 256, 0, stream>>>(
            ff, W2B + (size_t)l * 1024 * 4096, 4096, 1024,
            b2 + l * 1024, x, nullptr, nullptr, nullptr);
    }
    cvt_out<<<MTOT * DMODEL / 1024, 256, 0, stream>>>(x, (float*)d_out);
}